// Round 3
// baseline (751.144 us; speedup 1.0000x reference)
//
#include <hip/hip_runtime.h>
#include <math.h>
#include <type_traits>

typedef __bf16 bf16;
typedef __attribute__((ext_vector_type(8))) __bf16 bf16x8;
typedef __attribute__((ext_vector_type(4))) float f32x4;

#define SEQ 2048
#define DM 1024
#define NH 16
#define HD 64
#define BATCH 4

#define NEG_BIG (-1e30f)

__device__ inline bf16x8 cvt_f32x8(const float* p) {
  f32x4 x0 = *(const f32x4*)p;
  f32x4 x1 = *(const f32x4*)(p + 4);
  bf16x8 r;
  r[0] = (bf16)x0[0]; r[1] = (bf16)x0[1]; r[2] = (bf16)x0[2]; r[3] = (bf16)x0[3];
  r[4] = (bf16)x1[0]; r[5] = (bf16)x1[1]; r[6] = (bf16)x1[2]; r[7] = (bf16)x1[3];
  return r;
}

// ---------------------------------------------------------------------------
// Weight transpose + f32->bf16 convert: Wt[n][k] = (bf16)W[k][n], 1024x1024.
// blockIdx.z selects which of the 4 weight matrices.
// LDS row stride 66 -> 2-way max bank aliasing (free per m136).
// ---------------------------------------------------------------------------
__global__ __launch_bounds__(256) void transpose_w_kernel(
    const float* __restrict__ Wq, const float* __restrict__ Wk,
    const float* __restrict__ Wv, const float* __restrict__ Wo,
    bf16* __restrict__ Tq, bf16* __restrict__ Tk,
    bf16* __restrict__ Tv, bf16* __restrict__ To) {
  __shared__ bf16 tile[64 * 66];
  int z = blockIdx.z;
  const float* src = (z == 0) ? Wq : (z == 1) ? Wk : (z == 2) ? Wv : Wo;
  bf16* dst = (z == 0) ? Tq : (z == 1) ? Tk : (z == 2) ? Tv : To;
  int n0 = blockIdx.x * 64, k0 = blockIdx.y * 64;
  int t = threadIdx.x;
  int c = t & 63, rr = t >> 6;
#pragma unroll
  for (int i = 0; i < 16; i++) {
    int k = i * 4 + rr;
    tile[k * 66 + c] = (bf16)src[(size_t)(k0 + k) * DM + n0 + c];  // coalesced
  }
  __syncthreads();
#pragma unroll
  for (int i = 0; i < 16; i++) {
    int n = i * 4 + rr;
    dst[(size_t)(n0 + n) * DM + k0 + c] = tile[c * 66 + n];  // coalesced write
  }
}

// ---------------------------------------------------------------------------
// V transpose (bf16 -> bf16): Vn[b,s,h*64+d] -> Vt[((b*16+h)*64+d)*2048 + s]
// Vt lives in d_out's first 17 MB (d_out is 32 MB f32, dead until final GEMM).
// ---------------------------------------------------------------------------
__global__ __launch_bounds__(256) void transpose_v_kernel(
    const bf16* __restrict__ Vn, bf16* __restrict__ Vt) {
  __shared__ bf16 tile[64 * 66];
  int s0 = blockIdx.x * 64;
  int h = blockIdx.y, b = blockIdx.z;
  int t = threadIdx.x;
  int c = t & 63, rr = t >> 6;
#pragma unroll
  for (int i = 0; i < 16; i++) {
    int s = i * 4 + rr;
    tile[s * 66 + c] = Vn[((size_t)(b * SEQ + s0 + s)) * DM + h * HD + c];
  }
  __syncthreads();
#pragma unroll
  for (int i = 0; i < 16; i++) {
    int d = i * 4 + rr;
    Vt[((size_t)(b * NH + h) * HD + d) * SEQ + s0 + c] = tile[c * 66 + d];
  }
}

// ---------------------------------------------------------------------------
// GEMM + bias: C[8192,1024] = A[8192,1024] @ Bt[1024,1024]^T + bias
// AT = float (projections: cvt to bf16 during staging) or bf16 (final GEMM).
// CT = bf16 (intermediates) or float (final output).
// 128x128 tile, BK=32, 4 waves each computing 64x64 via 4x4 mfma 16x16x32.
// LDS k-outer layout [kc][row][8]: all b128 ops at the bank-floor.
// ---------------------------------------------------------------------------
template <typename AT, typename CT>
__global__ __launch_bounds__(256) void gemm_bias_kernel(
    const AT* __restrict__ A, const bf16* __restrict__ Bt,
    const float* __restrict__ bias, CT* __restrict__ C) {
  __shared__ bf16 As[4 * 128 * 8];
  __shared__ bf16 Bs[4 * 128 * 8];
  int m0 = blockIdx.x * 128, n0 = blockIdx.y * 128;
  int t = threadIdx.x;
  int wave = t >> 6, lane = t & 63, lr = lane & 15, lq = lane >> 4;
  int wm = (wave & 1) * 64, wn = (wave >> 1) * 64;

  f32x4 acc[4][4];
#pragma unroll
  for (int i = 0; i < 4; i++)
#pragma unroll
    for (int j = 0; j < 4; j++) acc[i][j] = (f32x4){0.f, 0.f, 0.f, 0.f};

  int rA = t >> 2;   // 0..63 (row within tile; +64 for second chunk)
  int kcA = t & 3;   // k-chunk 0..3
  const AT* pa = A + (size_t)(m0 + rA) * DM + kcA * 8;
  const bf16* pb = Bt + (size_t)(n0 + rA) * DM + kcA * 8;

  for (int k0 = 0; k0 < DM; k0 += 32) {
    bf16x8 a0, a1;
    if constexpr (std::is_same_v<AT, float>) {
      a0 = cvt_f32x8(pa);
      a1 = cvt_f32x8(pa + (size_t)64 * DM);
    } else {
      a0 = *(const bf16x8*)(pa);
      a1 = *(const bf16x8*)(pa + (size_t)64 * DM);
    }
    bf16x8 b0 = *(const bf16x8*)(pb);
    bf16x8 b1 = *(const bf16x8*)(pb + (size_t)64 * DM);
    pa += 32;
    pb += 32;
    *(bf16x8*)&As[(kcA * 128 + rA) * 8] = a0;
    *(bf16x8*)&As[(kcA * 128 + rA + 64) * 8] = a1;
    *(bf16x8*)&Bs[(kcA * 128 + rA) * 8] = b0;
    *(bf16x8*)&Bs[(kcA * 128 + rA + 64) * 8] = b1;
    __syncthreads();

    bf16x8 af[4], bfr[4];
#pragma unroll
    for (int i = 0; i < 4; i++)
      af[i] = *(const bf16x8*)&As[(lq * 128 + wm + i * 16 + lr) * 8];
#pragma unroll
    for (int j = 0; j < 4; j++)
      bfr[j] = *(const bf16x8*)&Bs[(lq * 128 + wn + j * 16 + lr) * 8];
#pragma unroll
    for (int i = 0; i < 4; i++)
#pragma unroll
      for (int j = 0; j < 4; j++)
        acc[i][j] = __builtin_amdgcn_mfma_f32_16x16x32_bf16(af[i], bfr[j],
                                                            acc[i][j], 0, 0, 0);
    __syncthreads();
  }

  // Epilogue: C/D layout col = lane&15, row = (lane>>4)*4 + reg
#pragma unroll
  for (int j = 0; j < 4; j++) {
    int col = n0 + wn + j * 16 + lr;
    float bv = bias[col];
#pragma unroll
    for (int i = 0; i < 4; i++) {
      int row = m0 + wm + i * 16 + lq * 4;
#pragma unroll
      for (int r = 0; r < 4; r++) {
        C[(size_t)(row + r) * DM + col] = (CT)(acc[i][j][r] + bv);
      }
    }
  }
}

// ---------------------------------------------------------------------------
// Flash attention (causal). One block per (q-tile=128, head, batch).
// 4 waves; wave w owns q rows [w*32, w*32+32) = 2 m-tiles.
// K tile LDS [8 kc][128 kv][8]  (d-chunks of K rows)
// Vt tile LDS [16 kc][64 d][8]  (kv-chunks of V^T rows)
// P LDS       [16 kc][128 q][8] (kv-chunks; C-layout -> A-layout round trip)
// No INF anywhere: finite NEG_BIG sentinel -> every exp arg finite.
// ---------------------------------------------------------------------------
__global__ __launch_bounds__(256) void attention_kernel(
    const bf16* __restrict__ Q, const bf16* __restrict__ K,
    const bf16* __restrict__ Vt, bf16* __restrict__ ctx) {
  __shared__ bf16 Ks[8 * 128 * 8];
  __shared__ bf16 Vs[16 * 64 * 8];
  __shared__ bf16 Ps[16 * 128 * 8];

  int qt = blockIdx.x, h = blockIdx.y, b = blockIdx.z;
  int q0 = qt * 128;
  int t = threadIdx.x, wave = t >> 6, lane = t & 63, lr = lane & 15,
      lq = lane >> 4;
  int wq = wave * 32;

  // Q fragments live in registers for the whole block (reused every K-tile)
  bf16x8 qf[2][2];
#pragma unroll
  for (int mi = 0; mi < 2; mi++)
#pragma unroll
    for (int ks = 0; ks < 2; ks++)
      qf[mi][ks] = *(const bf16x8*)&Q[(size_t)(b * SEQ + q0 + wq + mi * 16 + lr) * DM +
                                      h * HD + ks * 32 + lq * 8];

  f32x4 o[2][4];
  float mrow[2][4], lrow[2][4];
#pragma unroll
  for (int mi = 0; mi < 2; mi++) {
#pragma unroll
    for (int dj = 0; dj < 4; dj++) o[mi][dj] = (f32x4){0.f, 0.f, 0.f, 0.f};
#pragma unroll
    for (int r = 0; r < 4; r++) {
      mrow[mi][r] = NEG_BIG;
      lrow[mi][r] = 0.f;
    }
  }

  int rK = t >> 3, cK = t & 7;    // K staging: 8 lanes cover one row's 128 B
  int dV = t >> 4, cV = t & 15;   // V staging: 16 lanes cover one d-row's 256 B

  for (int kt = 0; kt <= qt; kt++) {
    int kv0 = kt * 128;
    __syncthreads();  // protect LDS from previous iteration's readers
#pragma unroll
    for (int i = 0; i < 4; i++) {
      int r = rK + i * 32;
      *(bf16x8*)&Ks[(cK * 128 + r) * 8] =
          *(const bf16x8*)&K[(size_t)(b * SEQ + kv0 + r) * DM + h * HD + cK * 8];
      int d = dV + i * 16;
      *(bf16x8*)&Vs[(cV * 64 + d) * 8] =
          *(const bf16x8*)&Vt[((size_t)(b * NH + h) * HD + d) * SEQ + kv0 + cV * 8];
    }
    __syncthreads();

    // S = Q K^T
    f32x4 s[2][8];
#pragma unroll
    for (int mi = 0; mi < 2; mi++)
#pragma unroll
      for (int nj = 0; nj < 8; nj++) s[mi][nj] = (f32x4){0.f, 0.f, 0.f, 0.f};
#pragma unroll
    for (int ks = 0; ks < 2; ks++)
#pragma unroll
      for (int nj = 0; nj < 8; nj++) {
        bf16x8 bfr = *(const bf16x8*)&Ks[((ks * 4 + lq) * 128 + nj * 16 + lr) * 8];
        s[0][nj] = __builtin_amdgcn_mfma_f32_16x16x32_bf16(qf[0][ks], bfr,
                                                           s[0][nj], 0, 0, 0);
        s[1][nj] = __builtin_amdgcn_mfma_f32_16x16x32_bf16(qf[1][ks], bfr,
                                                           s[1][nj], 0, 0, 0);
      }

    // scale + causal mask (diag tile only); finite sentinel, no INF
    bool diag = (kt == qt);
#pragma unroll
    for (int mi = 0; mi < 2; mi++)
#pragma unroll
      for (int nj = 0; nj < 8; nj++)
#pragma unroll
        for (int r = 0; r < 4; r++) {
          float v = s[mi][nj][r] * 0.125f;
          if (diag && (nj * 16 + lr > wq + mi * 16 + lq * 4 + r)) v = NEG_BIG;
          s[mi][nj][r] = v;
        }

    // online softmax; rows live in quads (row = lq*4 + r), reduce over 16 lanes
#pragma unroll
    for (int mi = 0; mi < 2; mi++)
#pragma unroll
      for (int r = 0; r < 4; r++) {
        float mx = s[mi][0][r];
#pragma unroll
        for (int nj = 1; nj < 8; nj++) mx = fmaxf(mx, s[mi][nj][r]);
        mx = fmaxf(mx, __shfl_xor(mx, 1));
        mx = fmaxf(mx, __shfl_xor(mx, 2));
        mx = fmaxf(mx, __shfl_xor(mx, 4));
        mx = fmaxf(mx, __shfl_xor(mx, 8));
        float mnew = fmaxf(mrow[mi][r], mx);
        float alpha = __expf(mrow[mi][r] - mnew);  // exp(-1e30) = 0, finite
        mrow[mi][r] = mnew;
        float rs = 0.f;
#pragma unroll
        for (int nj = 0; nj < 8; nj++) {
          float p = __expf(s[mi][nj][r] - mnew);  // masked -> exp(~-1e30)=0
          s[mi][nj][r] = p;
          rs += p;
        }
        rs += __shfl_xor(rs, 1);
        rs += __shfl_xor(rs, 2);
        rs += __shfl_xor(rs, 4);
        rs += __shfl_xor(rs, 8);
        lrow[mi][r] = lrow[mi][r] * alpha + rs;
#pragma unroll
        for (int dj = 0; dj < 4; dj++) o[mi][dj][r] *= alpha;
      }

    // P: C-layout regs -> A-layout LDS (bf16).
#pragma unroll
    for (int mi = 0; mi < 2; mi++)
#pragma unroll
      for (int nj = 0; nj < 8; nj++)
#pragma unroll
        for (int r = 0; r < 4; r++) {
          int row = wq + mi * 16 + lq * 4 + r;
          int col = nj * 16 + lr;
          Ps[((col >> 3) * 128 + row) * 8 + (col & 7)] = (bf16)s[mi][nj][r];
        }

    // Order P writes before the b128 reads (defeats any compiler reordering).
    __syncthreads();

    // O += P V
#pragma unroll
    for (int ks = 0; ks < 4; ks++) {
      bf16x8 pa0 = *(const bf16x8*)&Ps[((ks * 4 + lq) * 128 + wq + lr) * 8];
      bf16x8 pa1 = *(const bf16x8*)&Ps[((ks * 4 + lq) * 128 + wq + 16 + lr) * 8];
#pragma unroll
      for (int dj = 0; dj < 4; dj++) {
        bf16x8 vfr = *(const bf16x8*)&Vs[((ks * 4 + lq) * 64 + dj * 16 + lr) * 8];
        o[0][dj] = __builtin_amdgcn_mfma_f32_16x16x32_bf16(pa0, vfr, o[0][dj],
                                                           0, 0, 0);
        o[1][dj] = __builtin_amdgcn_mfma_f32_16x16x32_bf16(pa1, vfr, o[1][dj],
                                                           0, 0, 0);
      }
    }
  }

  // normalize + store ctx (natural [B,S,DM] layout for the output GEMM)
#pragma unroll
  for (int mi = 0; mi < 2; mi++)
#pragma unroll
    for (int r = 0; r < 4; r++) {
      float inv = 1.f / lrow[mi][r];
      int row = q0 + wq + mi * 16 + lq * 4 + r;
#pragma unroll
      for (int dj = 0; dj < 4; dj++) {
        int col = h * HD + dj * 16 + lr;
        ctx[(size_t)(b * SEQ + row) * DM + col] = (bf16)(o[mi][dj][r] * inv);
      }
    }
}

// ---------------------------------------------------------------------------
// I/O dtypes (per reference): ALL inputs float32, output float32 (32 MB).
// Internals bf16. Workspace layout (56 MB of d_ws):
//   ws[0,8MB)    4x transposed+converted weights, bf16 (2MB each)
//   ws[8,24MB)   Q   [B,S,DM] bf16
//   ws[24,40MB)  K   [B,S,DM] bf16
//   ws[40,56MB)  V natural bf16; aliased as ctx after V-transpose
//   d_out[0,17MB) V^T bf16 scratch (d_out is 32MB f32, dead until final GEMM)
// ---------------------------------------------------------------------------
extern "C" void kernel_launch(void* const* d_in, const int* in_sizes, int n_in,
                              void* d_out, int out_size, void* d_ws,
                              size_t ws_size, hipStream_t stream) {
  const float* iq = (const float*)d_in[0];
  const float* ik = (const float*)d_in[1];
  const float* iv = (const float*)d_in[2];
  const float* Wq = (const float*)d_in[3];
  const float* bq = (const float*)d_in[4];
  const float* Wk = (const float*)d_in[5];
  const float* bk = (const float*)d_in[6];
  const float* Wv = (const float*)d_in[7];
  const float* bv = (const float*)d_in[8];
  const float* Wo = (const float*)d_in[9];
  const float* bo = (const float*)d_in[10];

  char* ws = (char*)d_ws;
  const size_t MB = 1024 * 1024;
  bf16* Tq = (bf16*)(ws + 0 * MB);
  bf16* Tk = (bf16*)(ws + 2 * MB);
  bf16* Tv = (bf16*)(ws + 4 * MB);
  bf16* To = (bf16*)(ws + 6 * MB);
  bf16* Qp = (bf16*)(ws + 8 * MB);
  bf16* Kp = (bf16*)(ws + 24 * MB);
  bf16* Vp = (bf16*)(ws + 40 * MB);
  bf16* Vtp = (bf16*)d_out;  // d_out as V^T scratch (dead until final GEMM)
  bf16* Cx = Vp;             // ctx aliases V-natural (dead after transpose_v)

  transpose_w_kernel<<<dim3(16, 16, 4), 256, 0, stream>>>(Wq, Wk, Wv, Wo, Tq,
                                                          Tk, Tv, To);
  gemm_bias_kernel<float, bf16><<<dim3(64, 8), 256, 0, stream>>>(iq, Tq, bq, Qp);
  gemm_bias_kernel<float, bf16><<<dim3(64, 8), 256, 0, stream>>>(ik, Tk, bk, Kp);
  gemm_bias_kernel<float, bf16><<<dim3(64, 8), 256, 0, stream>>>(iv, Tv, bv, Vp);
  transpose_v_kernel<<<dim3(32, 16, 4), 256, 0, stream>>>(Vp, Vtp);
  attention_kernel<<<dim3(16, 16, 4), 256, 0, stream>>>(Qp, Kp, Vtp, Cx);
  gemm_bias_kernel<bf16, float><<<dim3(64, 8), 256, 0, stream>>>(
      Cx, To, bo, (float*)d_out);
}

// Round 4
// 453.751 us; speedup vs baseline: 1.6554x; 1.6554x over previous
//
#include <hip/hip_runtime.h>
#include <math.h>
#include <type_traits>

typedef __bf16 bf16;
typedef __attribute__((ext_vector_type(8))) __bf16 bf16x8;
typedef __attribute__((ext_vector_type(4))) float f32x4;

#define SEQ 2048
#define DM 1024
#define NH 16
#define HD 64
#define BATCH 4

#define NEG_BIG (-1e30f)
// softmax in exp2 domain: p = 2^(s * (1/8) * log2(e))
#define SCALE_L2E 0.18033688011f

__device__ inline bf16x8 cvt_f32x8(const float* p) {
  f32x4 x0 = *(const f32x4*)p;
  f32x4 x1 = *(const f32x4*)(p + 4);
  bf16x8 r;
  r[0] = (bf16)x0[0]; r[1] = (bf16)x0[1]; r[2] = (bf16)x0[2]; r[3] = (bf16)x0[3];
  r[4] = (bf16)x1[0]; r[5] = (bf16)x1[1]; r[6] = (bf16)x1[2]; r[7] = (bf16)x1[3];
  return r;
}

// ---------------------------------------------------------------------------
// Weight transpose + f32->bf16 convert: Wt[n][k] = (bf16)W[k][n], 1024x1024.
// ---------------------------------------------------------------------------
__global__ __launch_bounds__(256) void transpose_w_kernel(
    const float* __restrict__ Wq, const float* __restrict__ Wk,
    const float* __restrict__ Wv, const float* __restrict__ Wo,
    bf16* __restrict__ Tq, bf16* __restrict__ Tk,
    bf16* __restrict__ Tv, bf16* __restrict__ To) {
  __shared__ bf16 tile[64 * 66];
  int z = blockIdx.z;
  const float* src = (z == 0) ? Wq : (z == 1) ? Wk : (z == 2) ? Wv : Wo;
  bf16* dst = (z == 0) ? Tq : (z == 1) ? Tk : (z == 2) ? Tv : To;
  int n0 = blockIdx.x * 64, k0 = blockIdx.y * 64;
  int t = threadIdx.x;
  int c = t & 63, rr = t >> 6;
#pragma unroll
  for (int i = 0; i < 16; i++) {
    int k = i * 4 + rr;
    tile[k * 66 + c] = (bf16)src[(size_t)(k0 + k) * DM + n0 + c];
  }
  __syncthreads();
#pragma unroll
  for (int i = 0; i < 16; i++) {
    int n = i * 4 + rr;
    dst[(size_t)(n0 + n) * DM + k0 + c] = tile[c * 66 + n];
  }
}

// ---------------------------------------------------------------------------
// V transpose (bf16 -> bf16): Vn[b,s,h*64+d] -> Vt[((b*16+h)*64+d)*2048 + s]
// ---------------------------------------------------------------------------
__global__ __launch_bounds__(256) void transpose_v_kernel(
    const bf16* __restrict__ Vn, bf16* __restrict__ Vt) {
  __shared__ bf16 tile[64 * 66];
  int s0 = blockIdx.x * 64;
  int h = blockIdx.y, b = blockIdx.z;
  int t = threadIdx.x;
  int c = t & 63, rr = t >> 6;
#pragma unroll
  for (int i = 0; i < 16; i++) {
    int s = i * 4 + rr;
    tile[s * 66 + c] = Vn[((size_t)(b * SEQ + s0 + s)) * DM + h * HD + c];
  }
  __syncthreads();
#pragma unroll
  for (int i = 0; i < 16; i++) {
    int d = i * 4 + rr;
    Vt[((size_t)(b * NH + h) * HD + d) * SEQ + s0 + c] = tile[c * 66 + d];
  }
}

// ---------------------------------------------------------------------------
// GEMM + bias (unchanged from round 3 — passes; optimize next round)
// ---------------------------------------------------------------------------
template <typename AT, typename CT>
__global__ __launch_bounds__(256) void gemm_bias_kernel(
    const AT* __restrict__ A, const bf16* __restrict__ Bt,
    const float* __restrict__ bias, CT* __restrict__ C) {
  __shared__ bf16 As[4 * 128 * 8];
  __shared__ bf16 Bs[4 * 128 * 8];
  int m0 = blockIdx.x * 128, n0 = blockIdx.y * 128;
  int t = threadIdx.x;
  int wave = t >> 6, lane = t & 63, lr = lane & 15, lq = lane >> 4;
  int wm = (wave & 1) * 64, wn = (wave >> 1) * 64;

  f32x4 acc[4][4];
#pragma unroll
  for (int i = 0; i < 4; i++)
#pragma unroll
    for (int j = 0; j < 4; j++) acc[i][j] = (f32x4){0.f, 0.f, 0.f, 0.f};

  int rA = t >> 2;
  int kcA = t & 3;
  const AT* pa = A + (size_t)(m0 + rA) * DM + kcA * 8;
  const bf16* pb = Bt + (size_t)(n0 + rA) * DM + kcA * 8;

  for (int k0 = 0; k0 < DM; k0 += 32) {
    bf16x8 a0, a1;
    if constexpr (std::is_same_v<AT, float>) {
      a0 = cvt_f32x8(pa);
      a1 = cvt_f32x8(pa + (size_t)64 * DM);
    } else {
      a0 = *(const bf16x8*)(pa);
      a1 = *(const bf16x8*)(pa + (size_t)64 * DM);
    }
    bf16x8 b0 = *(const bf16x8*)(pb);
    bf16x8 b1 = *(const bf16x8*)(pb + (size_t)64 * DM);
    pa += 32;
    pb += 32;
    *(bf16x8*)&As[(kcA * 128 + rA) * 8] = a0;
    *(bf16x8*)&As[(kcA * 128 + rA + 64) * 8] = a1;
    *(bf16x8*)&Bs[(kcA * 128 + rA) * 8] = b0;
    *(bf16x8*)&Bs[(kcA * 128 + rA + 64) * 8] = b1;
    __syncthreads();

    bf16x8 af[4], bfr[4];
#pragma unroll
    for (int i = 0; i < 4; i++)
      af[i] = *(const bf16x8*)&As[(lq * 128 + wm + i * 16 + lr) * 8];
#pragma unroll
    for (int j = 0; j < 4; j++)
      bfr[j] = *(const bf16x8*)&Bs[(lq * 128 + wn + j * 16 + lr) * 8];
#pragma unroll
    for (int i = 0; i < 4; i++)
#pragma unroll
      for (int j = 0; j < 4; j++)
        acc[i][j] = __builtin_amdgcn_mfma_f32_16x16x32_bf16(af[i], bfr[j],
                                                            acc[i][j], 0, 0, 0);
    __syncthreads();
  }

#pragma unroll
  for (int j = 0; j < 4; j++) {
    int col = n0 + wn + j * 16 + lr;
    float bv = bias[col];
#pragma unroll
    for (int i = 0; i < 4; i++) {
      int row = m0 + wm + i * 16 + lq * 4;
#pragma unroll
      for (int r = 0; r < 4; r++) {
        C[(size_t)(row + r) * DM + col] = (CT)(acc[i][j][r] + bv);
      }
    }
  }
}

// ---------------------------------------------------------------------------
// Flash attention v2 (causal): zero LDS, zero barriers, wave-independent.
//
// Each wave owns a causally-complementary PAIR of 32-row q-tiles (p, 63-p)
// within one (b,h) -> uniform 2080 kv-rows of work per wave (no tail).
// 2048 waves total = 2 waves/SIMD.
//
// Trick: compute S^T = K·Q^T (A=K-frag from global, B=Q-frag in regs; q lands
// on MFMA *columns* = lane&15). Softmax over kv = in-register reduction over
// 16 per-lane values + shfl_xor 16,32. P (C-layout) -> A-operand of O = P·V
// via register shuffles (2 shfl + 1 select per element); V^T-frag is a direct
// 16B global load. O accumulates in C-layout with q on rows -> one 8-shuffle
// alpha-transpose per iteration.
// ---------------------------------------------------------------------------
__global__ __launch_bounds__(256, 2) void attention_kernel(
    const bf16* __restrict__ Q, const bf16* __restrict__ K,
    const bf16* __restrict__ Vt, bf16* __restrict__ ctx) {
  int h = blockIdx.y, b = blockIdx.z;
  int t = threadIdx.x, wave = t >> 6, lane = t & 63, lr = lane & 15,
      lq = lane >> 4;
  int p = blockIdx.x * 4 + wave;  // pair index in [0,32)

  const bf16* Qb = Q + (size_t)b * SEQ * DM + h * HD;
  const bf16* Kb = K + (size_t)b * SEQ * DM + h * HD;
  const bf16* Vb = Vt + (size_t)(b * NH + h) * HD * SEQ;
  bf16* Cb = ctx + (size_t)b * SEQ * DM + h * HD;

#pragma unroll 1
  for (int pass = 0; pass < 2; pass++) {
    int tq = pass ? (63 - p) : p;  // 32-row q-tile index
    int q0 = tq * 32;

    // Q fragments (B-operand): B[n=q][k=d], n = lr, k = ks*32 + lq*8 + j
    bf16x8 qf[2][2];
#pragma unroll
    for (int qi = 0; qi < 2; qi++)
#pragma unroll
      for (int ks = 0; ks < 2; ks++)
        qf[qi][ks] = *(const bf16x8*)&Qb[(size_t)(q0 + qi * 16 + lr) * DM +
                                         ks * 32 + lq * 8];

    f32x4 o[2][4];  // O[mi(q)][dj(d)], C-layout: col=d=lr, row=q=lq*4+r
    float m_st[2], l_st[2];
#pragma unroll
    for (int mi = 0; mi < 2; mi++) {
#pragma unroll
      for (int dj = 0; dj < 4; dj++) o[mi][dj] = (f32x4){0.f, 0.f, 0.f, 0.f};
      m_st[mi] = NEG_BIG;
      l_st[mi] = 0.f;
    }

    int kv_end = q0 + 32;
#pragma unroll 1
    for (int kv0 = 0; kv0 < kv_end; kv0 += 64) {
      // --- stage K and V fragments from global (16B/lane each) ---
      bf16x8 kf[4][2];  // A[m=kv][k=d]: m = lr, k = ks*32 + lq*8 + j
#pragma unroll
      for (int kvt = 0; kvt < 4; kvt++)
#pragma unroll
        for (int ks = 0; ks < 2; ks++)
          kf[kvt][ks] = *(const bf16x8*)&Kb[(size_t)(kv0 + kvt * 16 + lr) * DM +
                                            ks * 32 + lq * 8];
      bf16x8 vf[4][2];  // B[n=d][k=kv]: n = lr, k = ks2*32 + lq*8 + j
#pragma unroll
      for (int dj = 0; dj < 4; dj++)
#pragma unroll
        for (int ks2 = 0; ks2 < 2; ks2++)
          vf[dj][ks2] = *(const bf16x8*)&Vb[(size_t)(dj * 16 + lr) * SEQ + kv0 +
                                            ks2 * 32 + lq * 8];

      // --- S^T = K Q^T : C col = q = lr-of-result... (col=lane&15 = q) ---
      f32x4 s[4][2];  // s[kvt][qi]: row = kv = kvt*16 + lq*4 + r, col q = lr
#pragma unroll
      for (int kvt = 0; kvt < 4; kvt++)
#pragma unroll
        for (int qi = 0; qi < 2; qi++) {
          f32x4 acc = (f32x4){0.f, 0.f, 0.f, 0.f};
          acc = __builtin_amdgcn_mfma_f32_16x16x32_bf16(kf[kvt][0], qf[qi][0],
                                                        acc, 0, 0, 0);
          acc = __builtin_amdgcn_mfma_f32_16x16x32_bf16(kf[kvt][1], qf[qi][1],
                                                        acc, 0, 0, 0);
          s[kvt][qi] = acc;
        }

      // --- scale into exp2 domain + causal mask (only near diagonal) ---
      if (kv0 + 63 > q0) {
#pragma unroll
        for (int kvt = 0; kvt < 4; kvt++)
#pragma unroll
          for (int qi = 0; qi < 2; qi++)
#pragma unroll
            for (int r = 0; r < 4; r++) {
              int kv_g = kv0 + kvt * 16 + lq * 4 + r;
              int q_g = q0 + qi * 16 + lr;
              float v = s[kvt][qi][r] * SCALE_L2E;
              s[kvt][qi][r] = (kv_g > q_g) ? NEG_BIG : v;
            }
      } else {
#pragma unroll
        for (int kvt = 0; kvt < 4; kvt++)
#pragma unroll
          for (int qi = 0; qi < 2; qi++)
#pragma unroll
            for (int r = 0; r < 4; r++) s[kvt][qi][r] *= SCALE_L2E;
      }

      // --- online softmax (per q = lane column) ---
      float alpha[2];
#pragma unroll
      for (int qi = 0; qi < 2; qi++) {
        float mx = s[0][qi][0];
#pragma unroll
        for (int kvt = 0; kvt < 4; kvt++)
#pragma unroll
          for (int r = 0; r < 4; r++) mx = fmaxf(mx, s[kvt][qi][r]);
        mx = fmaxf(mx, __shfl_xor(mx, 16));
        mx = fmaxf(mx, __shfl_xor(mx, 32));
        float mnew = fmaxf(m_st[qi], mx);
        alpha[qi] = exp2f(m_st[qi] - mnew);
        m_st[qi] = mnew;
        float rs = 0.f;
#pragma unroll
        for (int kvt = 0; kvt < 4; kvt++)
#pragma unroll
          for (int r = 0; r < 4; r++) {
            float pv = exp2f(s[kvt][qi][r] - mnew);
            s[kvt][qi][r] = pv;
            rs += pv;
          }
        rs += __shfl_xor(rs, 16);
        rs += __shfl_xor(rs, 32);
        l_st[qi] = l_st[qi] * alpha[qi] + rs;
      }

      // --- alpha transpose (q on S-columns -> q on O-rows) + rescale O ---
      float aT[2][4];
#pragma unroll
      for (int mi = 0; mi < 2; mi++)
#pragma unroll
        for (int r = 0; r < 4; r++) aT[mi][r] = __shfl(alpha[mi], lq * 4 + r);
#pragma unroll
      for (int mi = 0; mi < 2; mi++)
#pragma unroll
        for (int dj = 0; dj < 4; dj++)
#pragma unroll
          for (int r = 0; r < 4; r++) o[mi][dj][r] *= aT[mi][r];

      // --- P (C-layout) -> A-operand fragments via shuffles, then O += P V ---
      int src_base = (lq & 1) * 32 + lr;  // (2*(lq&1))*16 + lr
      bool hi = (lq >> 1) != 0;
#pragma unroll
      for (int ks2 = 0; ks2 < 2; ks2++) {
        bf16x8 pf[2];
#pragma unroll
        for (int mi = 0; mi < 2; mi++) {
#pragma unroll
          for (int j = 0; j < 8; j++) {
            int src = src_base + (j >> 2) * 16;
            float v0 = __shfl(s[2 * ks2][mi][j & 3], src);
            float v1 = __shfl(s[2 * ks2 + 1][mi][j & 3], src);
            pf[mi][j] = (bf16)(hi ? v1 : v0);
          }
        }
#pragma unroll
        for (int dj = 0; dj < 4; dj++) {
          o[0][dj] = __builtin_amdgcn_mfma_f32_16x16x32_bf16(pf[0], vf[dj][ks2],
                                                             o[0][dj], 0, 0, 0);
          o[1][dj] = __builtin_amdgcn_mfma_f32_16x16x32_bf16(pf[1], vf[dj][ks2],
                                                             o[1][dj], 0, 0, 0);
        }
      }
    }

    // --- normalize + store (l transpose: q on columns -> rows) ---
    float lT[2][4];
#pragma unroll
    for (int mi = 0; mi < 2; mi++)
#pragma unroll
      for (int r = 0; r < 4; r++)
        lT[mi][r] = 1.f / __shfl(l_st[mi], lq * 4 + r);
#pragma unroll
    for (int mi = 0; mi < 2; mi++)
#pragma unroll
      for (int r = 0; r < 4; r++) {
        int row = q0 + mi * 16 + lq * 4 + r;
#pragma unroll
        for (int dj = 0; dj < 4; dj++)
          Cb[(size_t)row * DM + dj * 16 + lr] = (bf16)(o[mi][dj][r] * lT[mi][r]);
      }
  }
}

// ---------------------------------------------------------------------------
// I/O dtypes (per reference): ALL inputs float32, output float32 (32 MB).
// Internals bf16. Workspace layout (56 MB of d_ws):
//   ws[0,8MB)    4x transposed+converted weights, bf16 (2MB each)
//   ws[8,24MB)   Q   [B,S,DM] bf16
//   ws[24,40MB)  K   [B,S,DM] bf16
//   ws[40,56MB)  V natural bf16; aliased as ctx after V-transpose
//   d_out[0,17MB) V^T bf16 scratch (d_out is 32MB f32, dead until final GEMM)
// ---------------------------------------------------------------------------
extern "C" void kernel_launch(void* const* d_in, const int* in_sizes, int n_in,
                              void* d_out, int out_size, void* d_ws,
                              size_t ws_size, hipStream_t stream) {
  const float* iq = (const float*)d_in[0];
  const float* ik = (const float*)d_in[1];
  const float* iv = (const float*)d_in[2];
  const float* Wq = (const float*)d_in[3];
  const float* bq = (const float*)d_in[4];
  const float* Wk = (const float*)d_in[5];
  const float* bk = (const float*)d_in[6];
  const float* Wv = (const float*)d_in[7];
  const float* bv = (const float*)d_in[8];
  const float* Wo = (const float*)d_in[9];
  const float* bo = (const float*)d_in[10];

  char* ws = (char*)d_ws;
  const size_t MB = 1024 * 1024;
  bf16* Tq = (bf16*)(ws + 0 * MB);
  bf16* Tk = (bf16*)(ws + 2 * MB);
  bf16* Tv = (bf16*)(ws + 4 * MB);
  bf16* To = (bf16*)(ws + 6 * MB);
  bf16* Qp = (bf16*)(ws + 8 * MB);
  bf16* Kp = (bf16*)(ws + 24 * MB);
  bf16* Vp = (bf16*)(ws + 40 * MB);
  bf16* Vtp = (bf16*)d_out;  // d_out as V^T scratch (dead until final GEMM)
  bf16* Cx = Vp;             // ctx aliases V-natural (dead after transpose_v)

  transpose_w_kernel<<<dim3(16, 16, 4), 256, 0, stream>>>(Wq, Wk, Wv, Wo, Tq,
                                                          Tk, Tv, To);
  gemm_bias_kernel<float, bf16><<<dim3(64, 8), 256, 0, stream>>>(iq, Tq, bq, Qp);
  gemm_bias_kernel<float, bf16><<<dim3(64, 8), 256, 0, stream>>>(ik, Tk, bk, Kp);
  gemm_bias_kernel<float, bf16><<<dim3(64, 8), 256, 0, stream>>>(iv, Tv, bv, Vp);
  transpose_v_kernel<<<dim3(32, 16, 4), 256, 0, stream>>>(Vp, Vtp);
  attention_kernel<<<dim3(8, 16, 4), 256, 0, stream>>>(Qp, Kp, Vtp, Cx);
  gemm_bias_kernel<bf16, float><<<dim3(64, 8), 256, 0, stream>>>(
      Cx, To, bo, (float*)d_out);
}

// Round 5
// 402.097 us; speedup vs baseline: 1.8681x; 1.1285x over previous
//
#include <hip/hip_runtime.h>
#include <math.h>
#include <type_traits>

typedef __bf16 bf16;
typedef __attribute__((ext_vector_type(8))) __bf16 bf16x8;
typedef __attribute__((ext_vector_type(4))) float f32x4;

#define SEQ 2048
#define DM 1024
#define NH 16
#define HD 64
#define BATCH 4

#define NEG_BIG (-1e30f)
// softmax in exp2 domain: p = 2^(s * (1/8) * log2(e))
#define SCALE_L2E 0.18033688011f

__device__ inline bf16x8 cvt_f32x8(const float* p) {
  f32x4 x0 = *(const f32x4*)p;
  f32x4 x1 = *(const f32x4*)(p + 4);
  bf16x8 r;
  r[0] = (bf16)x0[0]; r[1] = (bf16)x0[1]; r[2] = (bf16)x0[2]; r[3] = (bf16)x0[3];
  r[4] = (bf16)x1[0]; r[5] = (bf16)x1[1]; r[6] = (bf16)x1[2]; r[7] = (bf16)x1[3];
  return r;
}

// async global->LDS DMA, 16 B per lane; lptr is wave-uniform base, HW writes
// lane i at lptr + i*16 (m97 pattern).
__device__ inline void async_copy16(const bf16* g, bf16* l) {
  __builtin_amdgcn_global_load_lds(
      (const __attribute__((address_space(1))) unsigned int*)g,
      (__attribute__((address_space(3))) unsigned int*)l, 16, 0, 0);
}

// ---------------------------------------------------------------------------
// f32 -> bf16 elementwise convert (memory-bound pre-pass), 8 elems/thread.
// ---------------------------------------------------------------------------
__global__ __launch_bounds__(256) void cvt_kernel(const float* __restrict__ src,
                                                  bf16* __restrict__ dst) {
  size_t i = ((size_t)blockIdx.x * 256 + threadIdx.x) * 8;
  *(bf16x8*)(dst + i) = cvt_f32x8(src + i);
}

// ---------------------------------------------------------------------------
// Weight transpose + f32->bf16 convert: Wt[n][k] = (bf16)W[k][n], 1024x1024.
// ---------------------------------------------------------------------------
__global__ __launch_bounds__(256) void transpose_w_kernel(
    const float* __restrict__ Wq, const float* __restrict__ Wk,
    const float* __restrict__ Wv, const float* __restrict__ Wo,
    bf16* __restrict__ Tq, bf16* __restrict__ Tk,
    bf16* __restrict__ Tv, bf16* __restrict__ To) {
  __shared__ bf16 tile[64 * 66];
  int z = blockIdx.z;
  const float* src = (z == 0) ? Wq : (z == 1) ? Wk : (z == 2) ? Wv : Wo;
  bf16* dst = (z == 0) ? Tq : (z == 1) ? Tk : (z == 2) ? Tv : To;
  int n0 = blockIdx.x * 64, k0 = blockIdx.y * 64;
  int t = threadIdx.x;
  int c = t & 63, rr = t >> 6;
#pragma unroll
  for (int i = 0; i < 16; i++) {
    int k = i * 4 + rr;
    tile[k * 66 + c] = (bf16)src[(size_t)(k0 + k) * DM + n0 + c];
  }
  __syncthreads();
#pragma unroll
  for (int i = 0; i < 16; i++) {
    int n = i * 4 + rr;
    dst[(size_t)(n0 + n) * DM + k0 + c] = tile[c * 66 + n];
  }
}

// ---------------------------------------------------------------------------
// V transpose (bf16 -> bf16): Vn[b,s,h*64+d] -> Vt[((b*16+h)*64+d)*2048 + s]
// ---------------------------------------------------------------------------
__global__ __launch_bounds__(256) void transpose_v_kernel(
    const bf16* __restrict__ Vn, bf16* __restrict__ Vt) {
  __shared__ bf16 tile[64 * 66];
  int s0 = blockIdx.x * 64;
  int h = blockIdx.y, b = blockIdx.z;
  int t = threadIdx.x;
  int c = t & 63, rr = t >> 6;
#pragma unroll
  for (int i = 0; i < 16; i++) {
    int s = i * 4 + rr;
    tile[s * 66 + c] = Vn[((size_t)(b * SEQ + s0 + s)) * DM + h * HD + c];
  }
  __syncthreads();
#pragma unroll
  for (int i = 0; i < 16; i++) {
    int d = i * 4 + rr;
    Vt[((size_t)(b * NH + h) * HD + d) * SEQ + s0 + c] = tile[c * 66 + d];
  }
}

// ---------------------------------------------------------------------------
// GEMM + bias, m97-style: C[8192,1024] = A[8192,1024] @ Bt[1024,1024]^T + bias
// A is bf16 (pre-converted). Staging via global_load_lds width=16 (async DMA,
// no VGPR round-trip). LDS layout [row][kc 0..3][8] row-major: DMA packing is
// lane-contiguous (wave w stages rows [32w,32w+32), 4 lanes x 64B per row),
// fragment reads are single ds_read_b128.
// 128x128 tile, BK=32, 4 waves x (4x4) mfma_f32_16x16x32_bf16.
// ---------------------------------------------------------------------------
template <typename CT>
__global__ __launch_bounds__(256) void gemm_bias_kernel(
    const bf16* __restrict__ A, const bf16* __restrict__ Bt,
    const float* __restrict__ bias, CT* __restrict__ C) {
  __shared__ bf16 As[128 * 32];
  __shared__ bf16 Bs[128 * 32];
  int m0 = blockIdx.x * 128, n0 = blockIdx.y * 128;
  int t = threadIdx.x;
  int wave = t >> 6, lane = t & 63, lr = lane & 15, lq = lane >> 4;
  int wm = (wave & 1) * 64, wn = (wave >> 1) * 64;

  f32x4 acc[4][4];
#pragma unroll
  for (int i = 0; i < 4; i++)
#pragma unroll
    for (int j = 0; j < 4; j++) acc[i][j] = (f32x4){0.f, 0.f, 0.f, 0.f};

  // staging: wave w, chunk c: slot = w*128 + c*64 + lane; row = slot>>2,
  // kc = lane&3.  global: row-major, 4 lanes cover 64 contiguous bytes.
  int srow = wave * 32 + (lane >> 2);  // rows [32w, 32w+16) ; +16 for c=1
  int skc = lane & 3;
  const bf16* gA0 = A + (size_t)(m0 + srow) * DM + skc * 8;
  const bf16* gA1 = gA0 + (size_t)16 * DM;
  const bf16* gB0 = Bt + (size_t)(n0 + srow) * DM + skc * 8;
  const bf16* gB1 = gB0 + (size_t)16 * DM;
  bf16* lA0 = &As[(wave * 128) * 8];        // wave-uniform LDS bases
  bf16* lA1 = &As[(wave * 128 + 64) * 8];
  bf16* lB0 = &Bs[(wave * 128) * 8];
  bf16* lB1 = &Bs[(wave * 128 + 64) * 8];

  for (int k0 = 0; k0 < DM; k0 += 32) {
    async_copy16(gA0, lA0);
    async_copy16(gA1, lA1);
    async_copy16(gB0, lB0);
    async_copy16(gB1, lB1);
    gA0 += 32; gA1 += 32; gB0 += 32; gB1 += 32;
    __syncthreads();  // drains vmcnt -> DMA complete

    bf16x8 af[4], bfr[4];
#pragma unroll
    for (int i = 0; i < 4; i++)
      af[i] = *(const bf16x8*)&As[(wm + i * 16 + lr) * 32 + lq * 8];
#pragma unroll
    for (int j = 0; j < 4; j++)
      bfr[j] = *(const bf16x8*)&Bs[(wn + j * 16 + lr) * 32 + lq * 8];
#pragma unroll
    for (int i = 0; i < 4; i++)
#pragma unroll
      for (int j = 0; j < 4; j++)
        acc[i][j] = __builtin_amdgcn_mfma_f32_16x16x32_bf16(af[i], bfr[j],
                                                            acc[i][j], 0, 0, 0);
    __syncthreads();
  }

  // Epilogue: C/D layout col = lane&15, row = (lane>>4)*4 + reg
#pragma unroll
  for (int j = 0; j < 4; j++) {
    int col = n0 + wn + j * 16 + lr;
    float bv = bias[col];
#pragma unroll
    for (int i = 0; i < 4; i++) {
      int row = m0 + wm + i * 16 + lq * 4;
#pragma unroll
      for (int r = 0; r < 4; r++) {
        C[(size_t)(row + r) * DM + col] = (CT)(acc[i][j][r] + bv);
      }
    }
  }
}

// ---------------------------------------------------------------------------
// Flash attention v2 (causal): zero LDS, zero barriers, wave-independent.
// Each wave owns a causally-complementary PAIR of 32-row q-tiles (p, 63-p)
// within one (b,h) -> uniform 2080 kv-rows per wave. (unchanged from round 4)
// ---------------------------------------------------------------------------
__global__ __launch_bounds__(256, 2) void attention_kernel(
    const bf16* __restrict__ Q, const bf16* __restrict__ K,
    const bf16* __restrict__ Vt, bf16* __restrict__ ctx) {
  int h = blockIdx.y, b = blockIdx.z;
  int t = threadIdx.x, wave = t >> 6, lane = t & 63, lr = lane & 15,
      lq = lane >> 4;
  int p = blockIdx.x * 4 + wave;  // pair index in [0,32)

  const bf16* Qb = Q + (size_t)b * SEQ * DM + h * HD;
  const bf16* Kb = K + (size_t)b * SEQ * DM + h * HD;
  const bf16* Vb = Vt + (size_t)(b * NH + h) * HD * SEQ;
  bf16* Cb = ctx + (size_t)b * SEQ * DM + h * HD;

#pragma unroll 1
  for (int pass = 0; pass < 2; pass++) {
    int tq = pass ? (63 - p) : p;
    int q0 = tq * 32;

    bf16x8 qf[2][2];
#pragma unroll
    for (int qi = 0; qi < 2; qi++)
#pragma unroll
      for (int ks = 0; ks < 2; ks++)
        qf[qi][ks] = *(const bf16x8*)&Qb[(size_t)(q0 + qi * 16 + lr) * DM +
                                         ks * 32 + lq * 8];

    f32x4 o[2][4];
    float m_st[2], l_st[2];
#pragma unroll
    for (int mi = 0; mi < 2; mi++) {
#pragma unroll
      for (int dj = 0; dj < 4; dj++) o[mi][dj] = (f32x4){0.f, 0.f, 0.f, 0.f};
      m_st[mi] = NEG_BIG;
      l_st[mi] = 0.f;
    }

    int kv_end = q0 + 32;
#pragma unroll 1
    for (int kv0 = 0; kv0 < kv_end; kv0 += 64) {
      bf16x8 kf[4][2];
#pragma unroll
      for (int kvt = 0; kvt < 4; kvt++)
#pragma unroll
        for (int ks = 0; ks < 2; ks++)
          kf[kvt][ks] = *(const bf16x8*)&Kb[(size_t)(kv0 + kvt * 16 + lr) * DM +
                                            ks * 32 + lq * 8];
      bf16x8 vf[4][2];
#pragma unroll
      for (int dj = 0; dj < 4; dj++)
#pragma unroll
        for (int ks2 = 0; ks2 < 2; ks2++)
          vf[dj][ks2] = *(const bf16x8*)&Vb[(size_t)(dj * 16 + lr) * SEQ + kv0 +
                                            ks2 * 32 + lq * 8];

      f32x4 s[4][2];
#pragma unroll
      for (int kvt = 0; kvt < 4; kvt++)
#pragma unroll
        for (int qi = 0; qi < 2; qi++) {
          f32x4 acc = (f32x4){0.f, 0.f, 0.f, 0.f};
          acc = __builtin_amdgcn_mfma_f32_16x16x32_bf16(kf[kvt][0], qf[qi][0],
                                                        acc, 0, 0, 0);
          acc = __builtin_amdgcn_mfma_f32_16x16x32_bf16(kf[kvt][1], qf[qi][1],
                                                        acc, 0, 0, 0);
          s[kvt][qi] = acc;
        }

      if (kv0 + 63 > q0) {
#pragma unroll
        for (int kvt = 0; kvt < 4; kvt++)
#pragma unroll
          for (int qi = 0; qi < 2; qi++)
#pragma unroll
            for (int r = 0; r < 4; r++) {
              int kv_g = kv0 + kvt * 16 + lq * 4 + r;
              int q_g = q0 + qi * 16 + lr;
              float v = s[kvt][qi][r] * SCALE_L2E;
              s[kvt][qi][r] = (kv_g > q_g) ? NEG_BIG : v;
            }
      } else {
#pragma unroll
        for (int kvt = 0; kvt < 4; kvt++)
#pragma unroll
          for (int qi = 0; qi < 2; qi++)
#pragma unroll
            for (int r = 0; r < 4; r++) s[kvt][qi][r] *= SCALE_L2E;
      }

      float alpha[2];
#pragma unroll
      for (int qi = 0; qi < 2; qi++) {
        float mx = s[0][qi][0];
#pragma unroll
        for (int kvt = 0; kvt < 4; kvt++)
#pragma unroll
          for (int r = 0; r < 4; r++) mx = fmaxf(mx, s[kvt][qi][r]);
        mx = fmaxf(mx, __shfl_xor(mx, 16));
        mx = fmaxf(mx, __shfl_xor(mx, 32));
        float mnew = fmaxf(m_st[qi], mx);
        alpha[qi] = exp2f(m_st[qi] - mnew);
        m_st[qi] = mnew;
        float rs = 0.f;
#pragma unroll
        for (int kvt = 0; kvt < 4; kvt++)
#pragma unroll
          for (int r = 0; r < 4; r++) {
            float pv = exp2f(s[kvt][qi][r] - mnew);
            s[kvt][qi][r] = pv;
            rs += pv;
          }
        rs += __shfl_xor(rs, 16);
        rs += __shfl_xor(rs, 32);
        l_st[qi] = l_st[qi] * alpha[qi] + rs;
      }

      float aT[2][4];
#pragma unroll
      for (int mi = 0; mi < 2; mi++)
#pragma unroll
        for (int r = 0; r < 4; r++) aT[mi][r] = __shfl(alpha[mi], lq * 4 + r);
#pragma unroll
      for (int mi = 0; mi < 2; mi++)
#pragma unroll
        for (int dj = 0; dj < 4; dj++)
#pragma unroll
          for (int r = 0; r < 4; r++) o[mi][dj][r] *= aT[mi][r];

      int src_base = (lq & 1) * 32 + lr;
      bool hi = (lq >> 1) != 0;
#pragma unroll
      for (int ks2 = 0; ks2 < 2; ks2++) {
        bf16x8 pf[2];
#pragma unroll
        for (int mi = 0; mi < 2; mi++) {
#pragma unroll
          for (int j = 0; j < 8; j++) {
            int src = src_base + (j >> 2) * 16;
            float v0 = __shfl(s[2 * ks2][mi][j & 3], src);
            float v1 = __shfl(s[2 * ks2 + 1][mi][j & 3], src);
            pf[mi][j] = (bf16)(hi ? v1 : v0);
          }
        }
#pragma unroll
        for (int dj = 0; dj < 4; dj++) {
          o[0][dj] = __builtin_amdgcn_mfma_f32_16x16x32_bf16(pf[0], vf[dj][ks2],
                                                             o[0][dj], 0, 0, 0);
          o[1][dj] = __builtin_amdgcn_mfma_f32_16x16x32_bf16(pf[1], vf[dj][ks2],
                                                             o[1][dj], 0, 0, 0);
        }
      }
    }

    float lT[2][4];
#pragma unroll
    for (int mi = 0; mi < 2; mi++)
#pragma unroll
      for (int r = 0; r < 4; r++)
        lT[mi][r] = 1.f / __shfl(l_st[mi], lq * 4 + r);
#pragma unroll
    for (int mi = 0; mi < 2; mi++)
#pragma unroll
      for (int r = 0; r < 4; r++) {
        int row = q0 + mi * 16 + lq * 4 + r;
#pragma unroll
        for (int dj = 0; dj < 4; dj++)
          Cb[(size_t)row * DM + dj * 16 + lr] = (bf16)(o[mi][dj][r] * lT[mi][r]);
      }
  }
}

// ---------------------------------------------------------------------------
// I/O: ALL inputs float32, output float32 (32 MB). Internals bf16.
// ws (56 MB):  [0,8)MB 4x Wt bf16 | [8,24) Qp | [24,40) Kp | [40,56) Vp/Cx
// d_out reuse: X (bf16 cvt buffer, 16.8 MB) for the 3 projections, then the
// same region holds V^T until the final GEMM overwrites d_out with f32 C.
// All sequential on one stream -> no liveness overlap.
// ---------------------------------------------------------------------------
extern "C" void kernel_launch(void* const* d_in, const int* in_sizes, int n_in,
                              void* d_out, int out_size, void* d_ws,
                              size_t ws_size, hipStream_t stream) {
  const float* iq = (const float*)d_in[0];
  const float* ik = (const float*)d_in[1];
  const float* iv = (const float*)d_in[2];
  const float* Wq = (const float*)d_in[3];
  const float* bq = (const float*)d_in[4];
  const float* Wk = (const float*)d_in[5];
  const float* bk = (const float*)d_in[6];
  const float* Wv = (const float*)d_in[7];
  const float* bv = (const float*)d_in[8];
  const float* Wo = (const float*)d_in[9];
  const float* bo = (const float*)d_in[10];

  char* ws = (char*)d_ws;
  const size_t MB = 1024 * 1024;
  bf16* Tq = (bf16*)(ws + 0 * MB);
  bf16* Tk = (bf16*)(ws + 2 * MB);
  bf16* Tv = (bf16*)(ws + 4 * MB);
  bf16* To = (bf16*)(ws + 6 * MB);
  bf16* Qp = (bf16*)(ws + 8 * MB);
  bf16* Kp = (bf16*)(ws + 24 * MB);
  bf16* Vp = (bf16*)(ws + 40 * MB);
  bf16* X = (bf16*)d_out;    // bf16 input-cvt buffer / later V^T scratch
  bf16* Vtp = (bf16*)d_out;  // same region, sequential reuse
  bf16* Cx = Vp;             // ctx aliases V-natural (dead after transpose_v)

  transpose_w_kernel<<<dim3(16, 16, 4), 256, 0, stream>>>(Wq, Wk, Wv, Wo, Tq,
                                                          Tk, Tv, To);
  cvt_kernel<<<dim3(4096), 256, 0, stream>>>(iq, X);
  gemm_bias_kernel<bf16><<<dim3(64, 8), 256, 0, stream>>>(X, Tq, bq, Qp);
  cvt_kernel<<<dim3(4096), 256, 0, stream>>>(ik, X);
  gemm_bias_kernel<bf16><<<dim3(64, 8), 256, 0, stream>>>(X, Tk, bk, Kp);
  cvt_kernel<<<dim3(4096), 256, 0, stream>>>(iv, X);
  gemm_bias_kernel<bf16><<<dim3(64, 8), 256, 0, stream>>>(X, Tv, bv, Vp);
  transpose_v_kernel<<<dim3(32, 16, 4), 256, 0, stream>>>(Vp, Vtp);
  attention_kernel<<<dim3(8, 16, 4), 256, 0, stream>>>(Qp, Kp, Vtp, Cx);
  gemm_bias_kernel<float><<<dim3(64, 8), 256, 0, stream>>>(Cx, To, bo,
                                                           (float*)d_out);
}